// Round 2
// baseline (438.159 us; speedup 1.0000x reference)
//
#include <hip/hip_runtime.h>
#include <hip/hip_bf16.h>
#include <stdint.h>

// ======================================================================
// EMSA fused pipeline. Device dtype (bf16 vs f32) detected at runtime.
// Algebra:
//  * head-mix (tw) folded into expanded K' (Kp): QK^T+mix = one BT-GEMM
//  * softmax row-sums are 1  =>  instance-norm mean = 1/256 exactly
//  * Dev = P - 1/256; var = mean(Dev^2); out = (Dev@V)*rsqrt(var+eps)
//  * tb cancels in softmax (constant per row) -> dropped
// ======================================================================

typedef __bf16 bf16;
typedef __bf16 bf16x8 __attribute__((ext_vector_type(8)));
typedef float  f32x4  __attribute__((ext_vector_type(4)));

#define LDS_AS  __attribute__((address_space(3)))
#define GLOB_AS __attribute__((address_space(1)))

__device__ __forceinline__ void gload_lds16(const bf16* g, void* l) {
    __builtin_amdgcn_global_load_lds((const GLOB_AS void*)g, (LDS_AS void*)l, 16, 0, 0);
}

// ---------------- constants ----------------
#define NB   16
#define NQ   2304
#define DD   512
#define NHH  8
#define NKV  256

// workspace layout (bytes)
constexpr size_t OFF_WQT = 0;
constexpr size_t OFF_WKT = OFF_WQT + 512*512*2;
constexpr size_t OFF_WVT = OFF_WKT + 512*512*2;
constexpr size_t OFF_WOT = OFF_WVT + 512*512*2;
constexpr size_t OFF_X   = OFF_WOT + 512*512*2;                       // (16,256,512) bf16
constexpr size_t OFF_KT  = OFF_X  + (size_t)NB*NKV*DD*2;              // (16,256,512) bf16
constexpr size_t OFF_KP  = OFF_KT + (size_t)NB*NKV*DD*2;              // (16,8,256,512) bf16
constexpr size_t OFF_VT  = OFF_KP + (size_t)NB*NHH*NKV*DD*2;          // (16,8,64,256) bf16
constexpr size_t OFF_QF  = OFF_VT + (size_t)NB*NHH*64*NKV*2;          // (16,2304,512) bf16
constexpr size_t OFF_U   = OFF_QF + (size_t)NB*NQ*DD*2;               // (16,2304,512) bf16 (also canonical queries, dead before attn)
constexpr size_t OFF_SS  = OFF_U  + (size_t)NB*NQ*DD*2;               // 128 f32
constexpr size_t OFF_SM  = OFF_SS + 512;                              // small canonical bf16 (11840 elems)
constexpr size_t OFF_FLG = OFF_SM + 24064;                            // int flag

// small-region element offsets
#define SM_BQ  0
#define SM_BK  512
#define SM_BV  1024
#define SM_BO  1536
#define SM_SRW 2048
#define SM_SRB 10240
#define SM_LNG 10752
#define SM_LNB 11264
#define SM_TW  11776

// ---------------- dtype detection ----------------
// Inspect low-16-bit "bf16 exponent" of 512 u32 words of queries.
// bf16 data: exponents cluster near 127 (~100% in [100,150]).
// f32 data: low 16 bits are mantissa noise (~20% in range).
__global__ __launch_bounds__(64) void detect_dtype(const uint32_t* __restrict__ q,
                                                   int* __restrict__ flag)
{
    int t = threadIdx.x;
    int cnt = 0;
    #pragma unroll
    for (int i = 0; i < 8; i++) {
        uint32_t w = q[t*8 + i];
        int e = (w >> 7) & 0xFF;
        cnt += (e >= 100 && e <= 150) ? 1 : 0;
    }
    #pragma unroll
    for (int m = 1; m < 64; m <<= 1) cnt += __shfl_xor(cnt, m);
    if (t == 0) *flag = (cnt >= 384) ? 0 : 1;   // 0=bf16, 1=f32
}

// ---------------- input conversion ----------------
__global__ __launch_bounds__(256) void convert_q(const void* __restrict__ in,
                                                 bf16* __restrict__ out,
                                                 const int* __restrict__ flag)
{
    int idx = blockIdx.x * 256 + threadIdx.x;   // 2,359,296 chunks of 8
    bf16x8 r;
    if (*flag) {
        f32x4 a = ((const f32x4*)in)[(size_t)idx*2];
        f32x4 b = ((const f32x4*)in)[(size_t)idx*2 + 1];
        #pragma unroll
        for (int i = 0; i < 4; i++) { r[i] = (bf16)a[i]; r[i+4] = (bf16)b[i]; }
    } else {
        r = ((const bf16x8*)in)[idx];
    }
    ((bf16x8*)out)[idx] = r;
}

__global__ __launch_bounds__(256) void convert_small(
    const void* s0, const void* s1, const void* s2, const void* s3,
    const void* s4, const void* s5, const void* s6, const void* s7,
    const void* s8, bf16* __restrict__ dst, const int* __restrict__ flag)
{
    const void* srcs[9] = {s0,s1,s2,s3,s4,s5,s6,s7,s8};
    const int sizes[9]  = {512,512,512,512,8192,512,512,512,64};
    const int offs[9]   = {SM_BQ,SM_BK,SM_BV,SM_BO,SM_SRW,SM_SRB,SM_LNG,SM_LNB,SM_TW};
    int b = blockIdx.x;
    const void* s = srcs[b];
    int n = sizes[b], o = offs[b];
    bool f32 = (*flag != 0);
    for (int i = threadIdx.x; i < n; i += 256) {
        float v = f32 ? ((const float*)s)[i] : (float)((const bf16*)s)[i];
        dst[o + i] = (bf16)v;
    }
}

// ---------------- weight transpose (512x512), dtype-aware load ----------------
__global__ __launch_bounds__(256) void transpose512(
    const void* s0, const void* s1, const void* s2, const void* s3,
    bf16* __restrict__ d0, bf16* __restrict__ d1,
    bf16* __restrict__ d2, bf16* __restrict__ d3,
    const int* __restrict__ flag)
{
    __shared__ bf16 tile[32][33];
    bool f32 = (*flag != 0);
    int wsel = blockIdx.z;
    const void* src = wsel == 0 ? s0 : wsel == 1 ? s1 : wsel == 2 ? s2 : s3;
    bf16*       dst = wsel == 0 ? d0 : wsel == 1 ? d1 : wsel == 2 ? d2 : d3;
    int c0 = blockIdx.x * 32, n0 = blockIdx.y * 32;
    int tx = threadIdx.x, ty = threadIdx.y;   // (32,8)
    #pragma unroll
    for (int i = 0; i < 4; i++) {
        size_t idx = (size_t)(c0 + ty + i*8) * 512 + n0 + tx;
        tile[ty + i*8][tx] = f32 ? (bf16)((const float*)src)[idx] : ((const bf16*)src)[idx];
    }
    __syncthreads();
    #pragma unroll
    for (int i = 0; i < 4; i++)
        dst[(size_t)(n0 + ty + i*8) * 512 + c0 + tx] = tile[tx][ty + i*8];
}

// ---------------- depthwise 4x4/s3 conv + LayerNorm ----------------
__global__ __launch_bounds__(256) void sr_ln(
    const bf16* __restrict__ q, const bf16* __restrict__ sm, bf16* __restrict__ x)
{
    const bf16* srw  = sm + SM_SRW;
    const bf16* srb  = sm + SM_SRB;
    const bf16* g    = sm + SM_LNG;
    const bf16* beta = sm + SM_LNB;
    int bo = blockIdx.x;               // b*256 + ok
    int b  = bo >> 8, ok = bo & 255;
    int oh = ok >> 4, ow = ok & 15;
    int t  = threadIdx.x;

    float v[2];
    #pragma unroll
    for (int h = 0; h < 2; h++) {
        int ch = t + h*256;
        float acc = 0.f;
        #pragma unroll
        for (int kh = 0; kh < 4; kh++) {
            int ih = oh*3 - 1 + kh;          // -1..47
            if (ih < 0) continue;
            #pragma unroll
            for (int kw = 0; kw < 4; kw++) {
                int iw = ow*3 - 1 + kw;
                if (iw < 0) continue;
                acc += (float)q[((size_t)b*NQ + ih*48 + iw)*DD + ch]
                     * (float)srw[ch*16 + kh*4 + kw];
            }
        }
        v[h] = acc + (float)srb[ch];
    }
    float s = v[0] + v[1], s2 = v[0]*v[0] + v[1]*v[1];
    #pragma unroll
    for (int m = 1; m < 64; m <<= 1) { s += __shfl_xor(s, m); s2 += __shfl_xor(s2, m); }
    __shared__ float ps[4], ps2[4];
    if ((t & 63) == 0) { ps[t >> 6] = s; ps2[t >> 6] = s2; }
    __syncthreads();
    s  = ps[0] + ps[1] + ps[2] + ps[3];
    s2 = ps2[0] + ps2[1] + ps2[2] + ps2[3];
    float mu  = s * (1.f/512.f);
    float var = s2 * (1.f/512.f) - mu*mu;
    float inv = rsqrtf(var + 1e-5f);
    #pragma unroll
    for (int h = 0; h < 2; h++) {
        int ch = t + h*256;
        float y = (v[h] - mu) * inv * (float)g[ch] + (float)beta[ch];
        x[(size_t)bo * DD + ch] = (bf16)y;
    }
}

// ---------------- generic BT-GEMM: C(M,512) = A(M,512) @ Bt(512,512)^T + bias ----------------
// MODE 0: bf16 row-major store. MODE 1: V^T scatter. MODE 2: dtype-branch store (output).
template <int MODE>
__global__ __launch_bounds__(256) void gemm_bt(
    const bf16* __restrict__ A, const bf16* __restrict__ Bt,
    const bf16* __restrict__ bias, bf16* __restrict__ C,
    const int* __restrict__ of32)
{
    constexpr int K = 512;
    __shared__ bf16 Al[128 * 64];
    __shared__ bf16 Bl[128 * 64];
    const int m0 = blockIdx.x * 128, n0 = blockIdx.y * 128;
    const int t = threadIdx.x;
    const int lane = t & 63, w = t >> 6;
    const int wr = w >> 1, wc = w & 1;
    const int gg = lane >> 4, li = lane & 15;
    bool f32o = false;
    if (MODE == 2) f32o = (*of32 != 0);

    f32x4 acc[4][4] = {};

    for (int k0 = 0; k0 < K; k0 += 64) {
        #pragma unroll
        for (int p = 0; p < 4; p++) {
            int off = p*4096 + t*16;
            int row = off >> 7, col = (off & 127) >> 1;
            gload_lds16(A + (size_t)(m0 + row)*K + k0 + col, (char*)Al + off);
        }
        #pragma unroll
        for (int p = 0; p < 4; p++) {
            int off = p*4096 + t*16;
            int row = off >> 7, col = (off & 127) >> 1;
            gload_lds16(Bt + (size_t)(n0 + row)*K + k0 + col, (char*)Bl + off);
        }
        __syncthreads();
        #pragma unroll
        for (int kk = 0; kk < 2; kk++) {
            bf16x8 af[4], bfr[4];
            #pragma unroll
            for (int i = 0; i < 4; i++) {
                af[i]  = *(const bf16x8*)(Al + (wr*64 + i*16 + li)*64 + kk*32 + gg*8);
                bfr[i] = *(const bf16x8*)(Bl + (wc*64 + i*16 + li)*64 + kk*32 + gg*8);
            }
            #pragma unroll
            for (int i = 0; i < 4; i++)
                #pragma unroll
                for (int j = 0; j < 4; j++)
                    acc[i][j] = __builtin_amdgcn_mfma_f32_16x16x32_bf16(af[i], bfr[j], acc[i][j], 0, 0, 0);
        }
        __syncthreads();
    }

    #pragma unroll
    for (int i = 0; i < 4; i++) {
        #pragma unroll
        for (int j = 0; j < 4; j++) {
            int rbase = m0 + wr*64 + i*16 + gg*4;
            int c     = n0 + wc*64 + j*16 + li;
            float bv = (float)bias[c];
            #pragma unroll
            for (int jj = 0; jj < 4; jj++) {
                float val = acc[i][j][jj] + bv;
                int r = rbase + jj;
                if (MODE == 1) {
                    // r = b*256+kk ; c = h*64+dv  ->  VT[((b*8+h)*64+dv)*256 + kk]
                    int bb = r >> 8, kk2 = r & 255;
                    int hh = c >> 6, dv = c & 63;
                    C[(((size_t)(bb*8 + hh))*64 + dv)*256 + kk2] = (bf16)val;
                } else if (MODE == 2) {
                    if (f32o) ((float*)C)[(size_t)r * 512 + c] = val;
                    else      C[(size_t)r * 512 + c] = (bf16)val;
                } else {
                    C[(size_t)r * 512 + c] = (bf16)val;
                }
            }
        }
    }
}

// ---------------- K' expansion: Kp[b,o,kk,c] = Kt[b,kk,c] * tw[o, c/64] / 8 ----------------
__global__ __launch_bounds__(256) void expand_kp(
    const bf16* __restrict__ Kt, const bf16* __restrict__ sm, bf16* __restrict__ Kp)
{
    const bf16* tw = sm + SM_TW;
    int idx = blockIdx.x * 256 + threadIdx.x;
    int c8 = idx & 63;
    int kk = (idx >> 6) & 255;
    int o  = (idx >> 14) & 7;
    int b  = idx >> 17;
    int hd = c8 >> 3;
    float s = (float)tw[o*8 + hd] * 0.125f;
    bf16x8 v = *(const bf16x8*)(Kt + (((size_t)b*256 + kk) << 9) + c8*8);
    bf16x8 r;
    #pragma unroll
    for (int i = 0; i < 8; i++) r[i] = (bf16)((float)v[i] * s);
    *(bf16x8*)(Kp + ((((size_t)(b*8 + o))*256 + kk) << 9) + c8*8) = r;
}

// ---------------- fused attention ----------------
__global__ __launch_bounds__(512) void attn_kernel(
    const bf16* __restrict__ Qf, const bf16* __restrict__ Kp,
    const bf16* __restrict__ VT, bf16* __restrict__ U, float* __restrict__ ssq_g)
{
    __shared__ bf16 Al[128 * 64];     // 16 KB
    __shared__ bf16 Bl[256 * 64];     // 32 KB
    __shared__ bf16 Pl[128 * 256];    // 64 KB (XOR-swizzled rows)
    __shared__ bf16 Vl[64 * 256];     // 32 KB (XOR-swizzled rows)
    __shared__ float prt[4][128];
    __shared__ float rpar[8];

    const int t = threadIdx.x;
    const int lane = t & 63, w = t >> 6;
    const int wr = w >> 2, wc = w & 3;        // wave grid 2(M) x 4(N)
    const int gg = lane >> 4, li = lane & 15;
    const int mt = blockIdx.x, o = blockIdx.y, b = blockIdx.z;
    const int q0 = mt * 128;

    const bf16* Abase = Qf + ((size_t)(b*NQ + q0)) * DD;
    const bf16* Bbase = Kp + ((size_t)((b*8 + o) * NKV)) * DD;
    const bf16* Vbase = VT + ((size_t)((b*8 + o) * 64)) * NKV;

    // stage V (64 x 256) into swizzled Vl
    #pragma unroll
    for (int p = 0; p < 4; p++) {
        int e = (p*512 + t) * 8;
        int dv = e >> 8, kk = e & 255;
        bf16x8 v = *(const bf16x8*)(Vbase + e);
        int byte = (dv << 9) + ((kk*2) ^ ((dv & 7) << 4));
        *(bf16x8*)((char*)Vl + byte) = v;
    }

    f32x4 acc[4][4] = {};

    for (int k0 = 0; k0 < 512; k0 += 64) {
        #pragma unroll
        for (int p = 0; p < 2; p++) {
            int off = p*8192 + t*16;
            int row = off >> 7, col = (off & 127) >> 1;
            gload_lds16(Abase + (size_t)row*DD + k0 + col, (char*)Al + off);
        }
        #pragma unroll
        for (int p = 0; p < 4; p++) {
            int off = p*8192 + t*16;
            int row = off >> 7, col = (off & 127) >> 1;
            gload_lds16(Bbase + (size_t)row*DD + k0 + col, (char*)Bl + off);
        }
        __syncthreads();
        #pragma unroll
        for (int kk = 0; kk < 2; kk++) {
            bf16x8 af[4], bfr[4];
            #pragma unroll
            for (int i = 0; i < 4; i++) {
                af[i]  = *(const bf16x8*)(Al + (wr*64 + i*16 + li)*64 + kk*32 + gg*8);
                bfr[i] = *(const bf16x8*)(Bl + (wc*64 + i*16 + li)*64 + kk*32 + gg*8);
            }
            #pragma unroll
            for (int i = 0; i < 4; i++)
                #pragma unroll
                for (int j = 0; j < 4; j++)
                    acc[i][j] = __builtin_amdgcn_mfma_f32_16x16x32_bf16(af[i], bfr[j], acc[i][j], 0, 0, 0);
        }
        __syncthreads();
    }

    // ---- softmax: clamp + exp + per-row partial sums (this wave's 64 cols) ----
    #pragma unroll
    for (int i = 0; i < 4; i++) {
        #pragma unroll
        for (int jj = 0; jj < 4; jj++) {
            float s = 0.f;
            #pragma unroll
            for (int j = 0; j < 4; j++) {
                float sc = fminf(fmaxf(acc[i][j][jj], -30.f), 30.f); // inert for correct data
                float e = __expf(sc);
                acc[i][j][jj] = e;
                s += e;
            }
            s += __shfl_xor(s, 1); s += __shfl_xor(s, 2);
            s += __shfl_xor(s, 4); s += __shfl_xor(s, 8);
            if (li == 0) prt[wc][wr*64 + i*16 + gg*4 + jj] = s;
        }
    }
    __syncthreads();

    // ---- P, Dev, sum of Dev^2, write Dev (bf16) to swizzled Pl ----
    float ssq = 0.f;
    #pragma unroll
    for (int i = 0; i < 4; i++) {
        #pragma unroll
        for (int jj = 0; jj < 4; jj++) {
            int r = wr*64 + i*16 + gg*4 + jj;
            float inv = 1.0f / (prt[0][r] + prt[1][r] + prt[2][r] + prt[3][r]);
            #pragma unroll
            for (int j = 0; j < 4; j++) {
                float dev = acc[i][j][jj] * inv - (1.0f/256.0f);
                ssq += dev * dev;
                int c = wc*64 + j*16 + li;
                int byte = (r << 9) + (((unsigned)(c*2)) ^ ((r & 7) << 4));
                *(bf16*)((char*)Pl + byte) = (bf16)dev;
            }
        }
    }
    #pragma unroll
    for (int m = 1; m < 64; m <<= 1) ssq += __shfl_xor(ssq, m);
    if (lane == 0) rpar[w] = ssq;
    __syncthreads();

    // ---- PV: each wave computes 16 rows x 64 dv ----
    f32x4 u[4] = {};
    const int rw = w * 16;
    #pragma unroll
    for (int ks = 0; ks < 8; ks++) {
        int r  = rw + li;
        int kb = (ks*32 + gg*8) * 2;
        bf16x8 pa = *(const bf16x8*)((char*)Pl + (r << 9) + (kb ^ ((r & 7) << 4)));
        #pragma unroll
        for (int n = 0; n < 4; n++) {
            int dv = n*16 + li;
            bf16x8 vb = *(const bf16x8*)((char*)Vl + (dv << 9) + (kb ^ ((dv & 7) << 4)));
            u[n] = __builtin_amdgcn_mfma_f32_16x16x32_bf16(pa, vb, u[n], 0, 0, 0);
        }
    }
    bf16* Ub = U + ((size_t)(b*NQ + q0)) * DD + o*64;
    #pragma unroll
    for (int n = 0; n < 4; n++)
        #pragma unroll
        for (int jj = 0; jj < 4; jj++)
            Ub[(size_t)(rw + gg*4 + jj) * DD + n*16 + li] = (bf16)u[n][jj];

    if (t == 0) {
        float tot = 0.f;
        #pragma unroll
        for (int i = 0; i < 8; i++) tot += rpar[i];
        atomicAdd(&ssq_g[b*8 + o], tot);
    }
}

// ---------------- U *= rsqrt(mean(Dev^2) + eps), in place ----------------
__global__ __launch_bounds__(256) void scale_u(bf16* __restrict__ U, const float* __restrict__ ssq)
{
    int cid = blockIdx.x * 256 + threadIdx.x;
    int c8 = cid & 63;
    int b  = (cid >> 6) / NQ;
    int h  = c8 >> 3;
    float va = ssq[b*8 + h] * (1.0f / ((float)NQ * (float)NKV));
    float s  = rsqrtf(va + 1e-5f);
    bf16x8 v = *(const bf16x8*)(U + (size_t)cid * 8);
    bf16x8 r;
    #pragma unroll
    for (int i = 0; i < 8; i++) r[i] = (bf16)((float)v[i] * s);
    *(bf16x8*)(U + (size_t)cid * 8) = r;
}

// ======================================================================
extern "C" void kernel_launch(void* const* d_in, const int* in_sizes, int n_in,
                              void* d_out, int out_size, void* d_ws, size_t ws_size,
                              hipStream_t stream)
{
    const void* queries = d_in[0];
    const void* Wq = d_in[1];  const void* bq = d_in[2];
    const void* Wk = d_in[3];  const void* bk = d_in[4];
    const void* Wv = d_in[5];  const void* bv = d_in[6];
    const void* Wo = d_in[7];  const void* bo = d_in[8];
    const void* srw = d_in[9]; const void* srb = d_in[10];
    const void* lng = d_in[11]; const void* lnb = d_in[12];
    const void* tw  = d_in[13];
    // d_in[14] = tb: cancels in softmax; unused.

    char* ws = (char*)d_ws;
    bf16* WqT = (bf16*)(ws + OFF_WQT);
    bf16* WkT = (bf16*)(ws + OFF_WKT);
    bf16* WvT = (bf16*)(ws + OFF_WVT);
    bf16* WoT = (bf16*)(ws + OFF_WOT);
    bf16* xb  = (bf16*)(ws + OFF_X);
    bf16* Kt  = (bf16*)(ws + OFF_KT);
    bf16* Kp  = (bf16*)(ws + OFF_KP);
    bf16* VTb = (bf16*)(ws + OFF_VT);
    bf16* Qf  = (bf16*)(ws + OFF_QF);
    bf16* Ub  = (bf16*)(ws + OFF_U);
    float* ss = (float*)(ws + OFF_SS);
    bf16* sm  = (bf16*)(ws + OFF_SM);
    int* flag = (int*)(ws + OFF_FLG);
    bf16* Qc  = Ub;   // canonical queries live in the U region (dead until attn)

    detect_dtype<<<dim3(1), dim3(64), 0, stream>>>((const uint32_t*)queries, flag);
    hipMemsetAsync(ss, 0, 128 * sizeof(float), stream);

    convert_q<<<dim3(9216), dim3(256), 0, stream>>>(queries, Qc, flag);
    convert_small<<<dim3(9), dim3(256), 0, stream>>>(bq, bk, bv, bo, srw, srb, lng, lnb, tw, sm, flag);
    transpose512<<<dim3(16, 16, 4), dim3(32, 8), 0, stream>>>(Wq, Wk, Wv, Wo, WqT, WkT, WvT, WoT, flag);

    sr_ln<<<dim3(NB * NKV), dim3(256), 0, stream>>>(Qc, sm, xb);
    gemm_bt<0><<<dim3(32, 4), dim3(256), 0, stream>>>(xb, WkT, sm + SM_BK, Kt, nullptr);
    gemm_bt<1><<<dim3(32, 4), dim3(256), 0, stream>>>(xb, WvT, sm + SM_BV, VTb, nullptr);
    expand_kp<<<dim3(8192), dim3(256), 0, stream>>>(Kt, sm, Kp);
    gemm_bt<0><<<dim3(288, 4), dim3(256), 0, stream>>>(Qc, WqT, sm + SM_BQ, Qf, nullptr);

    attn_kernel<<<dim3(18, 8, 16), dim3(512), 0, stream>>>(Qf, Kp, VTb, Ub, ss);
    scale_u<<<dim3(9216), dim3(256), 0, stream>>>(Ub, ss);
    gemm_bt<2><<<dim3(288, 4), dim3(256), 0, stream>>>(Ub, WoT, sm + SM_BO, (bf16*)d_out, flag);
}

// Round 3
// 376.422 us; speedup vs baseline: 1.1640x; 1.1640x over previous
//
#include <hip/hip_runtime.h>
#include <hip/hip_bf16.h>
#include <stdint.h>

// ======================================================================
// EMSA fused pipeline. Device dtype (bf16 vs f32) detected at runtime.
// Algebra:
//  * head-mix (tw) folded into expanded K' (Kp): QK^T+mix = one BT-GEMM
//  * softmax row-sums are 1  =>  instance-norm mean = 1/256 exactly
//  * Dev = P - 1/256; var = mean(Dev^2); out = (Dev@V)*rsqrt(var+eps)
//  * tb cancels in softmax (constant per row) -> dropped
//  * instance-norm scale folded into per-batch pre-scaled Wo^T
// R3: T2 both-sides swizzle on Al/Bl (attn+gemm), setprio, fused Kp
//     expansion into K-GEMM, scale_u folded into Wo.
// ======================================================================

typedef __bf16 bf16;
typedef __bf16 bf16x8 __attribute__((ext_vector_type(8)));
typedef float  f32x4  __attribute__((ext_vector_type(4)));

#define LDS_AS  __attribute__((address_space(3)))
#define GLOB_AS __attribute__((address_space(1)))

__device__ __forceinline__ void gload_lds16(const bf16* g, void* l) {
    __builtin_amdgcn_global_load_lds((const GLOB_AS void*)g, (LDS_AS void*)l, 16, 0, 0);
}

// ---------------- constants ----------------
#define NB   16
#define NQ   2304
#define DD   512
#define NHH  8
#define NKV  256

// workspace layout (bytes)
constexpr size_t OFF_WQT = 0;
constexpr size_t OFF_WKT = OFF_WQT + 512*512*2;
constexpr size_t OFF_WVT = OFF_WKT + 512*512*2;
constexpr size_t OFF_WOT = OFF_WVT + 512*512*2;
constexpr size_t OFF_X   = OFF_WOT + 512*512*2;                       // (16,256,512) bf16; later aliased by WoTp
constexpr size_t OFF_KT  = OFF_X  + (size_t)NB*NKV*DD*2;              // (dead; part of WoTp alias)
constexpr size_t OFF_KP  = OFF_KT + (size_t)NB*NKV*DD*2;              // (16,8,256,512) bf16
constexpr size_t OFF_VT  = OFF_KP + (size_t)NB*NHH*NKV*DD*2;          // (16,8,64,256) bf16
constexpr size_t OFF_QF  = OFF_VT + (size_t)NB*NHH*64*NKV*2;          // (16,2304,512) bf16
constexpr size_t OFF_U   = OFF_QF + (size_t)NB*NQ*DD*2;               // (16,2304,512) bf16 (also canonical queries)
constexpr size_t OFF_SS  = OFF_U  + (size_t)NB*NQ*DD*2;               // 128 f32
constexpr size_t OFF_SM  = OFF_SS + 512;                              // small canonical bf16
constexpr size_t OFF_FLG = OFF_SM + 24064;                            // int flag
constexpr size_t OFF_WOTP = OFF_X;                                    // (16,512,512) bf16 = 8 MB, aliases X+KT (dead by then)

// small-region element offsets
#define SM_BQ  0
#define SM_BK  512
#define SM_BV  1024
#define SM_BO  1536
#define SM_SRW 2048
#define SM_SRB 10240
#define SM_LNG 10752
#define SM_LNB 11264
#define SM_TW  11776

// ---------------- dtype detection ----------------
__global__ __launch_bounds__(64) void detect_dtype(const uint32_t* __restrict__ q,
                                                   int* __restrict__ flag)
{
    int t = threadIdx.x;
    int cnt = 0;
    #pragma unroll
    for (int i = 0; i < 8; i++) {
        uint32_t w = q[t*8 + i];
        int e = (w >> 7) & 0xFF;
        cnt += (e >= 100 && e <= 150) ? 1 : 0;
    }
    #pragma unroll
    for (int m = 1; m < 64; m <<= 1) cnt += __shfl_xor(cnt, m);
    if (t == 0) *flag = (cnt >= 384) ? 0 : 1;   // 0=bf16, 1=f32
}

// ---------------- input conversion ----------------
__global__ __launch_bounds__(256) void convert_q(const void* __restrict__ in,
                                                 bf16* __restrict__ out,
                                                 const int* __restrict__ flag)
{
    int idx = blockIdx.x * 256 + threadIdx.x;
    bf16x8 r;
    if (*flag) {
        f32x4 a = ((const f32x4*)in)[(size_t)idx*2];
        f32x4 b = ((const f32x4*)in)[(size_t)idx*2 + 1];
        #pragma unroll
        for (int i = 0; i < 4; i++) { r[i] = (bf16)a[i]; r[i+4] = (bf16)b[i]; }
    } else {
        r = ((const bf16x8*)in)[idx];
    }
    ((bf16x8*)out)[idx] = r;
}

__global__ __launch_bounds__(256) void convert_small(
    const void* s0, const void* s1, const void* s2, const void* s3,
    const void* s4, const void* s5, const void* s6, const void* s7,
    const void* s8, bf16* __restrict__ dst, const int* __restrict__ flag)
{
    const void* srcs[9] = {s0,s1,s2,s3,s4,s5,s6,s7,s8};
    const int sizes[9]  = {512,512,512,512,8192,512,512,512,64};
    const int offs[9]   = {SM_BQ,SM_BK,SM_BV,SM_BO,SM_SRW,SM_SRB,SM_LNG,SM_LNB,SM_TW};
    int b = blockIdx.x;
    const void* s = srcs[b];
    int n = sizes[b], o = offs[b];
    bool f32 = (*flag != 0);
    for (int i = threadIdx.x; i < n; i += 256) {
        float v = f32 ? ((const float*)s)[i] : (float)((const bf16*)s)[i];
        dst[o + i] = (bf16)v;
    }
}

// ---------------- weight transpose (512x512), dtype-aware load ----------------
__global__ __launch_bounds__(256) void transpose512(
    const void* s0, const void* s1, const void* s2, const void* s3,
    bf16* __restrict__ d0, bf16* __restrict__ d1,
    bf16* __restrict__ d2, bf16* __restrict__ d3,
    const int* __restrict__ flag)
{
    __shared__ bf16 tile[32][33];
    bool f32 = (*flag != 0);
    int wsel = blockIdx.z;
    const void* src = wsel == 0 ? s0 : wsel == 1 ? s1 : wsel == 2 ? s2 : s3;
    bf16*       dst = wsel == 0 ? d0 : wsel == 1 ? d1 : wsel == 2 ? d2 : d3;
    int c0 = blockIdx.x * 32, n0 = blockIdx.y * 32;
    int tx = threadIdx.x, ty = threadIdx.y;   // (32,8)
    #pragma unroll
    for (int i = 0; i < 4; i++) {
        size_t idx = (size_t)(c0 + ty + i*8) * 512 + n0 + tx;
        tile[ty + i*8][tx] = f32 ? (bf16)((const float*)src)[idx] : ((const bf16*)src)[idx];
    }
    __syncthreads();
    #pragma unroll
    for (int i = 0; i < 4; i++)
        dst[(size_t)(n0 + ty + i*8) * 512 + c0 + tx] = tile[tx][ty + i*8];
}

// ---------------- depthwise 4x4/s3 conv + LayerNorm ----------------
__global__ __launch_bounds__(256) void sr_ln(
    const bf16* __restrict__ q, const bf16* __restrict__ sm, bf16* __restrict__ x)
{
    const bf16* srw  = sm + SM_SRW;
    const bf16* srb  = sm + SM_SRB;
    const bf16* g    = sm + SM_LNG;
    const bf16* beta = sm + SM_LNB;
    int bo = blockIdx.x;               // b*256 + ok
    int b  = bo >> 8, ok = bo & 255;
    int oh = ok >> 4, ow = ok & 15;
    int t  = threadIdx.x;

    float v[2];
    #pragma unroll
    for (int h = 0; h < 2; h++) {
        int ch = t + h*256;
        float acc = 0.f;
        #pragma unroll
        for (int kh = 0; kh < 4; kh++) {
            int ih = oh*3 - 1 + kh;
            if (ih < 0) continue;
            #pragma unroll
            for (int kw = 0; kw < 4; kw++) {
                int iw = ow*3 - 1 + kw;
                if (iw < 0) continue;
                acc += (float)q[((size_t)b*NQ + ih*48 + iw)*DD + ch]
                     * (float)srw[ch*16 + kh*4 + kw];
            }
        }
        v[h] = acc + (float)srb[ch];
    }
    float s = v[0] + v[1], s2 = v[0]*v[0] + v[1]*v[1];
    #pragma unroll
    for (int m = 1; m < 64; m <<= 1) { s += __shfl_xor(s, m); s2 += __shfl_xor(s2, m); }
    __shared__ float ps[4], ps2[4];
    if ((t & 63) == 0) { ps[t >> 6] = s; ps2[t >> 6] = s2; }
    __syncthreads();
    s  = ps[0] + ps[1] + ps[2] + ps[3];
    s2 = ps2[0] + ps2[1] + ps2[2] + ps2[3];
    float mu  = s * (1.f/512.f);
    float var = s2 * (1.f/512.f) - mu*mu;
    float inv = rsqrtf(var + 1e-5f);
    #pragma unroll
    for (int h = 0; h < 2; h++) {
        int ch = t + h*256;
        float y = (v[h] - mu) * inv * (float)g[ch] + (float)beta[ch];
        x[(size_t)bo * DD + ch] = (bf16)y;
    }
}

// ---------------- generic BT-GEMM: C(M,512) = A(M,512) @ Bt(512,512)^T + bias ----------
// MODE 0: bf16 row-major store.
// MODE 1: V^T scatter store (b,h,dv,kk).
// MODE 2: output GEMM: per-batch Bt block (pre-scaled WoT), dtype-branch store.
// MODE 3: K-GEMM: write 8 tw-scaled Kp copies directly.
// Al/Bl use both-sides XOR swizzle: source chunk ^= row&7, read ^= (li&7)<<4.
template <int MODE>
__global__ __launch_bounds__(256) void gemm_bt(
    const bf16* __restrict__ A, const bf16* __restrict__ Bt,
    const bf16* __restrict__ bias, bf16* __restrict__ C,
    const int* __restrict__ of32, const bf16* __restrict__ sm)
{
    constexpr int K = 512;
    __shared__ bf16 Al[128 * 64];
    __shared__ bf16 Bl[128 * 64];
    const int m0 = blockIdx.x * 128, n0 = blockIdx.y * 128;
    const int t = threadIdx.x;
    const int lane = t & 63, w = t >> 6;
    const int wr = w >> 1, wc = w & 1;
    const int gg = lane >> 4, li = lane & 15;
    const int fsw = (li & 7) << 4;
    bool f32o = false;
    if (MODE == 2) f32o = (*of32 != 0);

    const bf16* Btb = Bt;
    if (MODE == 2) Btb = Bt + (size_t)(m0 / 2304) * (512 * 512);   // per-batch Wo'

    float s8[8];
    if (MODE == 3) {
        int h = (n0 >> 6) + wc;           // thread-constant head index
        #pragma unroll
        for (int o = 0; o < 8; o++) s8[o] = (float)sm[SM_TW + o*8 + h] * 0.125f;
    }

    f32x4 acc[4][4] = {};

    for (int k0 = 0; k0 < K; k0 += 64) {
        #pragma unroll
        for (int p = 0; p < 4; p++) {
            int off = p*4096 + t*16;
            int row = off >> 7;
            int col = ((((off >> 4) & 7) ^ (row & 7)) << 3);
            gload_lds16(A + (size_t)(m0 + row)*K + k0 + col, (char*)Al + off);
        }
        #pragma unroll
        for (int p = 0; p < 4; p++) {
            int off = p*4096 + t*16;
            int row = off >> 7;
            int col = ((((off >> 4) & 7) ^ (row & 7)) << 3);
            gload_lds16(Bt == Btb ? Bt + (size_t)(n0 + row)*K + k0 + col
                                  : Btb + (size_t)(n0 + row)*K + k0 + col, (char*)Bl + off);
        }
        __syncthreads();
        #pragma unroll
        for (int kk = 0; kk < 2; kk++) {
            bf16x8 af[4], bfr[4];
            #pragma unroll
            for (int i = 0; i < 4; i++) {
                af[i]  = *(const bf16x8*)((char*)Al + (wr*64 + i*16 + li)*128 + ((kk*64 + gg*16) ^ fsw));
                bfr[i] = *(const bf16x8*)((char*)Bl + (wc*64 + i*16 + li)*128 + ((kk*64 + gg*16) ^ fsw));
            }
            __builtin_amdgcn_s_setprio(1);
            #pragma unroll
            for (int i = 0; i < 4; i++)
                #pragma unroll
                for (int j = 0; j < 4; j++)
                    acc[i][j] = __builtin_amdgcn_mfma_f32_16x16x32_bf16(af[i], bfr[j], acc[i][j], 0, 0, 0);
            __builtin_amdgcn_s_setprio(0);
        }
        __syncthreads();
    }

    #pragma unroll
    for (int i = 0; i < 4; i++) {
        #pragma unroll
        for (int j = 0; j < 4; j++) {
            int rbase = m0 + wr*64 + i*16 + gg*4;
            int c     = n0 + wc*64 + j*16 + li;
            float bv = (float)bias[c];
            #pragma unroll
            for (int jj = 0; jj < 4; jj++) {
                float val = acc[i][j][jj] + bv;
                int r = rbase + jj;
                if (MODE == 1) {
                    int bb = r >> 8, kk2 = r & 255;
                    int hh = c >> 6, dv = c & 63;
                    C[(((size_t)(bb*8 + hh))*64 + dv)*256 + kk2] = (bf16)val;
                } else if (MODE == 2) {
                    if (f32o) ((float*)C)[(size_t)r * 512 + c] = val;
                    else      C[(size_t)r * 512 + c] = (bf16)val;
                } else if (MODE == 3) {
                    int bb = r >> 8, kk2 = r & 255;
                    #pragma unroll
                    for (int o = 0; o < 8; o++)
                        C[((size_t)((bb*8 + o)*256 + kk2))*512 + c] = (bf16)(val * s8[o]);
                } else {
                    C[(size_t)r * 512 + c] = (bf16)val;
                }
            }
        }
    }
}

// ---------------- per-batch scaled Wo^T: WoTp[b][c][c'] = WoT[c][c'] * s(b, c'/64) ----
__global__ __launch_bounds__(256) void scale_wot(const bf16* __restrict__ WoT,
                                                 const float* __restrict__ ssq,
                                                 bf16* __restrict__ out)
{
    int idx = blockIdx.x * 256 + threadIdx.x;   // 16*512*64 chunks of 8
    int c8 = idx & 63;
    int c  = (idx >> 6) & 511;
    int b  = idx >> 15;
    int h  = c8 >> 3;
    float va = ssq[b*8 + h] * (1.0f / ((float)NQ * (float)NKV));
    float s  = rsqrtf(va + 1e-5f);
    bf16x8 v = *(const bf16x8*)(WoT + ((size_t)c << 9) + c8*8);
    bf16x8 r;
    #pragma unroll
    for (int i = 0; i < 8; i++) r[i] = (bf16)((float)v[i] * s);
    *(bf16x8*)(out + ((size_t)idx << 3)) = r;
}

// ---------------- fused attention ----------------
__global__ __launch_bounds__(512) void attn_kernel(
    const bf16* __restrict__ Qf, const bf16* __restrict__ Kp,
    const bf16* __restrict__ VT, bf16* __restrict__ U, float* __restrict__ ssq_g)
{
    __shared__ bf16 Al[128 * 64];     // 16 KB
    __shared__ bf16 Bl[256 * 64];     // 32 KB
    __shared__ bf16 Pl[128 * 256];    // 64 KB (XOR-swizzled rows)
    __shared__ bf16 Vl[64 * 256];     // 32 KB (XOR-swizzled rows)
    __shared__ float prt[4][128];
    __shared__ float rpar[8];

    const int t = threadIdx.x;
    const int lane = t & 63, w = t >> 6;
    const int wr = w >> 2, wc = w & 3;        // wave grid 2(M) x 4(N)
    const int gg = lane >> 4, li = lane & 15;
    const int fsw = (li & 7) << 4;
    const int mt = blockIdx.x, o = blockIdx.y, b = blockIdx.z;
    const int q0 = mt * 128;

    const bf16* Abase = Qf + ((size_t)(b*NQ + q0)) * DD;
    const bf16* Bbase = Kp + ((size_t)((b*8 + o) * NKV)) * DD;
    const bf16* Vbase = VT + ((size_t)((b*8 + o) * 64)) * NKV;

    // stage V (64 x 256) into Vl via gload_lds, source pre-swizzled so that
    // phys layout == byte (dv<<9) + (kbyte ^ ((dv&7)<<4))
    #pragma unroll
    for (int p = 0; p < 4; p++) {
        int e = (p*512 + t) * 8;
        int dv = e >> 8, kc = (e >> 3) & 31;
        gload_lds16(Vbase + dv*256 + ((kc ^ (dv & 7)) << 3), (char*)Vl + e*2);
    }

    f32x4 acc[4][4] = {};

    for (int k0 = 0; k0 < 512; k0 += 64) {
        #pragma unroll
        for (int p = 0; p < 2; p++) {
            int off = p*8192 + t*16;
            int row = off >> 7;
            int col = ((((off >> 4) & 7) ^ (row & 7)) << 3);
            gload_lds16(Abase + (size_t)row*DD + k0 + col, (char*)Al + off);
        }
        #pragma unroll
        for (int p = 0; p < 4; p++) {
            int off = p*8192 + t*16;
            int row = off >> 7;
            int col = ((((off >> 4) & 7) ^ (row & 7)) << 3);
            gload_lds16(Bbase + (size_t)row*DD + k0 + col, (char*)Bl + off);
        }
        __syncthreads();
        #pragma unroll
        for (int kk = 0; kk < 2; kk++) {
            bf16x8 af[4], bfr[4];
            #pragma unroll
            for (int i = 0; i < 4; i++) {
                af[i]  = *(const bf16x8*)((char*)Al + (wr*64 + i*16 + li)*128 + ((kk*64 + gg*16) ^ fsw));
                bfr[i] = *(const bf16x8*)((char*)Bl + (wc*64 + i*16 + li)*128 + ((kk*64 + gg*16) ^ fsw));
            }
            __builtin_amdgcn_s_setprio(1);
            #pragma unroll
            for (int i = 0; i < 4; i++)
                #pragma unroll
                for (int j = 0; j < 4; j++)
                    acc[i][j] = __builtin_amdgcn_mfma_f32_16x16x32_bf16(af[i], bfr[j], acc[i][j], 0, 0, 0);
            __builtin_amdgcn_s_setprio(0);
        }
        __syncthreads();
    }

    // ---- softmax: clamp + exp + per-row partial sums ----
    #pragma unroll
    for (int i = 0; i < 4; i++) {
        #pragma unroll
        for (int jj = 0; jj < 4; jj++) {
            float s = 0.f;
            #pragma unroll
            for (int j = 0; j < 4; j++) {
                float sc = fminf(fmaxf(acc[i][j][jj], -30.f), 30.f);
                float e = __expf(sc);
                acc[i][j][jj] = e;
                s += e;
            }
            s += __shfl_xor(s, 1); s += __shfl_xor(s, 2);
            s += __shfl_xor(s, 4); s += __shfl_xor(s, 8);
            if (li == 0) prt[wc][wr*64 + i*16 + gg*4 + jj] = s;
        }
    }
    __syncthreads();

    // ---- P, Dev, sum of Dev^2, write Dev (bf16) to swizzled Pl ----
    float ssq = 0.f;
    #pragma unroll
    for (int i = 0; i < 4; i++) {
        #pragma unroll
        for (int jj = 0; jj < 4; jj++) {
            int r = wr*64 + i*16 + gg*4 + jj;
            float inv = 1.0f / (prt[0][r] + prt[1][r] + prt[2][r] + prt[3][r]);
            #pragma unroll
            for (int j = 0; j < 4; j++) {
                float dev = acc[i][j][jj] * inv - (1.0f/256.0f);
                ssq += dev * dev;
                int c = wc*64 + j*16 + li;
                int byte = (r << 9) + (((unsigned)(c*2)) ^ ((r & 7) << 4));
                *(bf16*)((char*)Pl + byte) = (bf16)dev;
            }
        }
    }
    #pragma unroll
    for (int m = 1; m < 64; m <<= 1) ssq += __shfl_xor(ssq, m);
    if (lane == 0) rpar[w] = ssq;
    __syncthreads();

    // ---- PV: each wave computes 16 rows x 64 dv ----
    f32x4 u[4] = {};
    const int rw = w * 16;
    #pragma unroll
    for (int ks = 0; ks < 8; ks++) {
        int r  = rw + li;
        int kb = (ks*32 + gg*8) * 2;
        bf16x8 pa = *(const bf16x8*)((char*)Pl + (r << 9) + (kb ^ ((r & 7) << 4)));
        __builtin_amdgcn_s_setprio(1);
        #pragma unroll
        for (int n = 0; n < 4; n++) {
            int dv = n*16 + li;
            bf16x8 vb = *(const bf16x8*)((char*)Vl + (dv << 9) + (kb ^ ((dv & 7) << 4)));
            u[n] = __builtin_amdgcn_mfma_f32_16x16x32_bf16(pa, vb, u[n], 0, 0, 0);
        }
        __builtin_amdgcn_s_setprio(0);
    }
    bf16* Ub = U + ((size_t)(b*NQ + q0)) * DD + o*64;
    #pragma unroll
    for (int n = 0; n < 4; n++)
        #pragma unroll
        for (int jj = 0; jj < 4; jj++)
            Ub[(size_t)(rw + gg*4 + jj) * DD + n*16 + li] = (bf16)u[n][jj];

    if (t == 0) {
        float tot = 0.f;
        #pragma unroll
        for (int i = 0; i < 8; i++) tot += rpar[i];
        atomicAdd(&ssq_g[b*8 + o], tot);
    }
}

// ======================================================================
extern "C" void kernel_launch(void* const* d_in, const int* in_sizes, int n_in,
                              void* d_out, int out_size, void* d_ws, size_t ws_size,
                              hipStream_t stream)
{
    const void* queries = d_in[0];
    const void* Wq = d_in[1];  const void* bq = d_in[2];
    const void* Wk = d_in[3];  const void* bk = d_in[4];
    const void* Wv = d_in[5];  const void* bv = d_in[6];
    const void* Wo = d_in[7];  const void* bo = d_in[8];
    const void* srw = d_in[9]; const void* srb = d_in[10];
    const void* lng = d_in[11]; const void* lnb = d_in[12];
    const void* tw  = d_in[13];
    // d_in[14] = tb: cancels in softmax; unused.

    char* ws = (char*)d_ws;
    bf16* WqT = (bf16*)(ws + OFF_WQT);
    bf16* WkT = (bf16*)(ws + OFF_WKT);
    bf16* WvT = (bf16*)(ws + OFF_WVT);
    bf16* WoT = (bf16*)(ws + OFF_WOT);
    bf16* xb  = (bf16*)(ws + OFF_X);
    bf16* Kp  = (bf16*)(ws + OFF_KP);
    bf16* VTb = (bf16*)(ws + OFF_VT);
    bf16* Qf  = (bf16*)(ws + OFF_QF);
    bf16* Ub  = (bf16*)(ws + OFF_U);
    float* ss = (float*)(ws + OFF_SS);
    bf16* sm  = (bf16*)(ws + OFF_SM);
    int* flag = (int*)(ws + OFF_FLG);
    bf16* WoTp = (bf16*)(ws + OFF_WOTP);   // aliases xb (+KT), dead by scale_wot time
    bf16* Qc  = Ub;                         // canonical queries in U region (dead until attn)

    detect_dtype<<<dim3(1), dim3(64), 0, stream>>>((const uint32_t*)queries, flag);
    hipMemsetAsync(ss, 0, 128 * sizeof(float), stream);

    convert_q<<<dim3(9216), dim3(256), 0, stream>>>(queries, Qc, flag);
    convert_small<<<dim3(9), dim3(256), 0, stream>>>(bq, bk, bv, bo, srw, srb, lng, lnb, tw, sm, flag);
    transpose512<<<dim3(16, 16, 4), dim3(32, 8), 0, stream>>>(Wq, Wk, Wv, Wo, WqT, WkT, WvT, WoT, flag);

    sr_ln<<<dim3(NB * NKV), dim3(256), 0, stream>>>(Qc, sm, xb);
    gemm_bt<3><<<dim3(32, 4), dim3(256), 0, stream>>>(xb, WkT, sm + SM_BK, Kp, nullptr, sm);
    gemm_bt<1><<<dim3(32, 4), dim3(256), 0, stream>>>(xb, WvT, sm + SM_BV, VTb, nullptr, sm);
    gemm_bt<0><<<dim3(288, 4), dim3(256), 0, stream>>>(Qc, WqT, sm + SM_BQ, Qf, nullptr, sm);

    attn_kernel<<<dim3(18, 8, 16), dim3(512), 0, stream>>>(Qf, Kp, VTb, Ub, ss);

    scale_wot<<<dim3(2048), dim3(256), 0, stream>>>(WoT, ss, WoTp);
    gemm_bt<2><<<dim3(288, 4), dim3(256), 0, stream>>>(Ub, WoTp, sm + SM_BO, (bf16*)d_out, flag, sm);
}